// Round 2
// baseline (458.549 us; speedup 1.0000x reference)
//
#include <hip/hip_runtime.h>

namespace {
constexpr int B_  = 4;
constexpr int C_  = 256;
constexpr int H_  = 80;
constexpr int W1_ = 184;
constexpr int W2_ = 184;
constexpr int G_  = 2;
constexpr int S_  = 9;
constexpr int L_  = 4;
constexpr int CH  = L_ * G_ * S_;   // 72 output channels
constexpr int TM  = 64;             // w1 rows per block
constexpr int TNP = 192;            // padded w2 (184 -> 192)
constexpr int KC  = 16;             // K chunk
constexpr int NCHUNK = C_ / KC;     // 16
constexpr int BUF = 4096;           // floats per staging buffer: A[16][64] + B[16][192]
// LDS: 2 x BUF staging (double-buffered). Epilogue union in [0, 5648):
//   corrS[16][192] floats [0,3072)   pyr[16][161] floats [3072,5648)
constexpr int LDS_FLOATS = 2 * BUF; // 8192 floats = 32 KB
}

#define GLOBAL_AS __attribute__((address_space(1)))
#define LDS_AS    __attribute__((address_space(3)))

__global__ __launch_bounds__(256, 2)
void corr1d_fused(const float* __restrict__ fmap1, const float* __restrict__ fmap2,
                  const float* __restrict__ coords, const float* __restrict__ sigma,
                  float* __restrict__ out)
{
    __shared__ float lds[LDS_FLOATS];

    const int tile   = blockIdx.x;        // 0..2
    const int bh     = blockIdx.y;        // 0..B*H-1
    const int b      = bh / H_;
    const int h      = bh - b * H_;
    const int w1base = tile * TM;

    const int tid  = threadIdx.x;
    const int tw2  = tid & 15;            // 16 col-groups of 12
    const int tw1  = tid >> 4;            // 16 row-groups of 4
    const int wave = tid >> 6;
    const int lane = tid & 63;

    float acc[4][12];
    #pragma unroll
    for (int i = 0; i < 4; ++i)
        #pragma unroll
        for (int j = 0; j < 12; ++j) acc[i][j] = 0.f;

    // ---- staging descriptors (global_load_lds: LDS dest = wave-uniform base + lane*16B) ----
    const int maxA = B_*C_*H_*W1_ - 4;
    const int maxB = B_*C_*H_*W2_ - 4;

    // A: wave w covers As floats [w*256, w*256+256) == rows kk=4w..4w+3, cols 0..63
    const int a_kk  = 4*wave + (lane >> 4);
    const int a_col = (lane & 15) * 4;
    const int aOff0 = ((b*C_ + a_kk)*H_ + h)*W1_ + w1base + a_col;
    const int aLds  = wave * 256;                       // float idx within buffer, wave-uniform

    // B: 3 loads per wave; flat float f = (wave*3+m)*256 + lane*4 -> kk = f/192, col = f%192
    int bOff0[3], bLdsI[3];
    #pragma unroll
    for (int m = 0; m < 3; ++m) {
        const int f    = (wave*3 + m)*256 + lane*4;
        const int kk   = f / TNP;
        const int col  = f - kk*TNP;
        const int colc = (col < W2_) ? col : 0;         // pad cols read garbage-in-bounds; never consumed
        bOff0[m] = ((b*C_ + kk)*H_ + h)*W2_ + colc;
        bLdsI[m] = 1024 + (wave*3 + m)*256;             // float idx within buffer, wave-uniform
    }

    const int stepA = KC * H_ * W1_;
    const int stepB = KC * H_ * W2_;

    // issue the 4 staging loads for chunk ck into buffer at float-offset bufOff
    auto stage = [&](int ck, int bufOff) {
        int ga = aOff0 + ck*stepA; ga = (ga > maxA) ? maxA : ga;
        __builtin_amdgcn_global_load_lds((const GLOBAL_AS void*)(fmap1 + ga),
                                         (LDS_AS void*)(lds + bufOff + aLds), 16, 0, 0);
        #pragma unroll
        for (int m = 0; m < 3; ++m) {
            int gb = bOff0[m] + ck*stepB; gb = (gb > maxB) ? maxB : gb;
            __builtin_amdgcn_global_load_lds((const GLOBAL_AS void*)(fmap2 + gb),
                                             (LDS_AS void*)(lds + bufOff + bLdsI[m]), 16, 0, 0);
        }
    };

    // 4x12 register-tile FMA over one staged chunk at float-offset bufOff
    auto compute = [&](int bufOff) {
        #pragma unroll
        for (int kk = 0; kk < KC; ++kk) {
            const float4 av  = *(const float4*)(lds + bufOff + kk*64 + tw1*4);
            const float4 bv0 = *(const float4*)(lds + bufOff + 1024 + kk*TNP + tw2*12);
            const float4 bv1 = *(const float4*)(lds + bufOff + 1024 + kk*TNP + tw2*12 + 4);
            const float4 bv2 = *(const float4*)(lds + bufOff + 1024 + kk*TNP + tw2*12 + 8);
            const float a0 = av.x, a1 = av.y, a2 = av.z, a3 = av.w;
            const float bb[12] = {bv0.x,bv0.y,bv0.z,bv0.w,
                                  bv1.x,bv1.y,bv1.z,bv1.w,
                                  bv2.x,bv2.y,bv2.z,bv2.w};
            #pragma unroll
            for (int j = 0; j < 12; ++j) {
                acc[0][j] = fmaf(a0, bb[j], acc[0][j]);
                acc[1][j] = fmaf(a1, bb[j], acc[1][j]);
                acc[2][j] = fmaf(a2, bb[j], acc[2][j]);
                acc[3][j] = fmaf(a3, bb[j], acc[3][j]);
            }
        }
    };

    // ---- K loop: double-buffered staging, counted vmcnt, raw barriers (T3/T4 pattern) ----
    // Steady state at the wait point: 4 loads of chunk ck (issued last iter) + 4 of chunk ck+1
    // (just issued) outstanding -> s_waitcnt vmcnt(4) retires exactly chunk ck's loads.
    stage(0, 0);
    #pragma unroll 1
    for (int ck = 0; ck < NCHUNK; ck += 2) {
        // even chunk: data in buf0, prefetch ck+1 (always valid: ck+1 <= 15) into buf1
        stage(ck + 1, BUF);
        asm volatile("s_waitcnt vmcnt(4)" ::: "memory");
        __builtin_amdgcn_s_barrier();
        asm volatile("" ::: "memory");
        compute(0);
        asm volatile("" ::: "memory");
        __builtin_amdgcn_s_barrier();

        // odd chunk: data in buf1, prefetch ck+2 into buf0 (unless done)
        if (ck + 2 < NCHUNK) {
            stage(ck + 2, 0);
            asm volatile("s_waitcnt vmcnt(4)" ::: "memory");
        } else {
            asm volatile("s_waitcnt vmcnt(0)" ::: "memory");
        }
        __builtin_amdgcn_s_barrier();
        asm volatile("" ::: "memory");
        compute(BUF);
        asm volatile("" ::: "memory");
        __builtin_amdgcn_s_barrier();
    }

    // ---- fused epilogue: 4 chunks of 16 rows ----
    float* corrS = lds;                                 // [16][192]
    float* pyr   = lds + 3072;                          // [16][161]: lvl1[92] lvl2[46] lvl3[23]
    constexpr float scale = 0.0625f;                    // 1/sqrt(256)

    for (int q = 0; q < 4; ++q) {
        // store this chunk's rows (owned by tw1 in [4q,4q+4))
        if ((tw1 >> 2) == q) {
            const int r0 = (tw1 & 3) * 4;
            #pragma unroll
            for (int i = 0; i < 4; ++i)
                #pragma unroll
                for (int j = 0; j < 12; ++j)
                    corrS[(r0 + i)*TNP + tw2*12 + j] = acc[i][j] * scale;
        }
        __syncthreads();

        // pooled pyramid levels, computed directly from level0 (no inter-level dep)
        for (int e = tid; e < 16*161; e += 256) {
            const int r = e / 161;
            const int p = e - r*161;
            const float* row = corrS + r*TNP;
            float v;
            if (p < 92) {
                const int j = 2*p;
                v = 0.5f * (row[j] + row[j+1]);
            } else if (p < 138) {
                const int j = (p - 92) * 4;
                v = 0.25f * (row[j] + row[j+1] + row[j+2] + row[j+3]);
            } else {
                const int j = (p - 138) * 8;
                v = 0.125f * (row[j]+row[j+1]+row[j+2]+row[j+3]
                             +row[j+4]+row[j+5]+row[j+6]+row[j+7]);
            }
            pyr[r*161 + p] = v;
        }
        __syncthreads();

        // Gaussian sampling: 72 channels x 16 rows; 16 consecutive lanes share a channel -> coalesced stores
        for (int t = tid; t < CH*16; t += 256) {
            const int ch = t >> 4;
            const int r  = t & 15;
            const int w1 = w1base + q*16 + r;
            if (w1 < W1_) {
                const int lvl = ch / (G_*S_);
                const int rem = ch - lvl*(G_*S_);
                const int g   = rem / S_;
                const int s   = rem - g*S_;
                const int cix = ((b*G_ + g)*H_ + h)*W1_ + w1;
                const float x  = (float)(s - S_/2) * sigma[cix] + coords[cix];
                const float xi = x * (1.0f / (float)(1 << lvl)); // exact pow2 scale
                const int   Wl = W2_ >> lvl;
                const float x0 = floorf(xi);
                const float wr = xi - x0;
                const int i0 = (int)x0;
                const int i1 = i0 + 1;
                const float* rowp = (lvl == 0) ? (corrS + r*TNP)
                                  : (pyr + r*161 + ((lvl == 1) ? 0 : (lvl == 2) ? 92 : 138));
                const int i0c = min(max(i0, 0), Wl - 1);
                const int i1c = min(max(i1, 0), Wl - 1);
                const float v0 = (i0 >= 0 && i0 < Wl) ? rowp[i0c] : 0.f;  // zero-pad mask
                const float v1 = (i1 >= 0 && i1 < Wl) ? rowp[i1c] : 0.f;
                out[((b*CH + ch)*H_ + h)*W1_ + w1] = (1.f - wr)*v0 + wr*v1;
            }
        }
        __syncthreads();                                // reads done before next chunk overwrites corrS
    }
}

extern "C" void kernel_launch(void* const* d_in, const int* in_sizes, int n_in,
                              void* d_out, int out_size, void* d_ws, size_t ws_size,
                              hipStream_t stream) {
    const float* fmap1  = (const float*)d_in[0];
    const float* fmap2  = (const float*)d_in[1];
    const float* coords = (const float*)d_in[2];
    const float* sigma  = (const float*)d_in[3];
    float* out = (float*)d_out;

    dim3 grid((W1_ + TM - 1) / TM, B_ * H_);   // 3 x 320
    corr1d_fused<<<grid, 256, 0, stream>>>(fmap1, fmap2, coords, sigma, out);
}

// Round 9
// 186.943 us; speedup vs baseline: 2.4529x; 2.4529x over previous
//
#include <hip/hip_runtime.h>

typedef short short8 __attribute__((ext_vector_type(8)));
typedef float f32x4  __attribute__((ext_vector_type(4)));

namespace {
constexpr int B_  = 4;
constexpr int C_  = 256;
constexpr int H_  = 80;
constexpr int W1_ = 184;
constexpr int W2_ = 184;
constexpr int G_  = 2;
constexpr int S_  = 9;
constexpr int CH  = 72;              // 4 levels * 2 gaussians * 9 samples
constexpr int TM  = 64;              // w1 rows per block
constexpr int HW1 = H_ * W1_;
constexpr int HW2 = H_ * W2_;
constexpr int NK  = 8;               // K chunks of 32 (C=256)
// LDS byte map (staging, 32 KB):
//   A_hi[64][32] bf16 @ 0      (4 KB)   A_lo @ 4096
//   B_hi[192][32] bf16 @ 8192  (12 KB)  B_lo @ 20480
// epilogue reuse: corrS[16][192] f32 @ 0, pyr[16][161] f32 @ float-idx 3072
}

struct HL { short hi, lo; };

// fp32 -> bf16 hi/lo split, RNE both terms. Residual after hi+lo ~ 2^-18 |x|.
// Returns by value: vector elements can't bind to non-const references.
__device__ __forceinline__ HL bsplit(float x) {
    HL r_;
    unsigned u = __builtin_bit_cast(unsigned, x);
    unsigned r = (u + 0x7fffu + ((u >> 16) & 1u)) & 0xffff0000u;
    r_.hi = (short)(r >> 16);
    float lof = x - __builtin_bit_cast(float, r);     // exact in fp32
    unsigned ul = __builtin_bit_cast(unsigned, lof);
    r_.lo = (short)((ul + 0x7fffu + ((ul >> 16) & 1u)) >> 16);
    return r_;
}

__global__ __launch_bounds__(256, 3)
void corr1d_mfma(const float* __restrict__ fmap1, const float* __restrict__ fmap2,
                 const float* __restrict__ coords, const float* __restrict__ sigma,
                 float* __restrict__ out)
{
    __shared__ __align__(16) char ldsRaw[32768];
    float* ldsF = (float*)ldsRaw;

    const int tile   = blockIdx.x;            // 0..2
    const int bh     = blockIdx.y;            // 0..319
    const int b      = bh / H_;
    const int h      = bh - b * H_;
    const int w1base = tile * TM;

    const int tid = threadIdx.x;
    const int l   = tid & 63;
    const int w   = __builtin_amdgcn_readfirstlane(tid >> 6);  // wave id, SGPR
    const int lm  = l & 15;
    const int kg  = l >> 4;

    // ---- fragment-read byte offsets (constant across chunks; XOR swizzle slot=kg^((row>>1)&3)) ----
    const int am   = 16 * w + lm;                                   // wave w owns m-tile w
    const int aOff = am * 64 + ((kg ^ ((am >> 1) & 3)) << 4);       // into A_hi @0
    int bOff[12];
    #pragma unroll
    for (int nt = 0; nt < 12; ++nt) {
        const int n = nt * 16 + lm;
        bOff[nt] = 8192 + n * 64 + ((kg ^ ((n >> 1) & 3)) << 4);    // into B_hi @8192
    }

    // ---- staging-write byte offsets (constant; writer k-group = wave id) ----
    const int aW = l * 64 + ((w ^ ((l >> 1) & 3)) << 4);            // A row = l
    const int nB0 = l, nB1 = 64 + l, nB2 = 128 + l;                 // B rows (p*64+l)
    const int bW0 = 8192 + nB0 * 64 + ((w ^ ((nB0 >> 1) & 3)) << 4);
    const int bW1 = 8192 + nB1 * 64 + ((w ^ ((nB1 >> 1) & 3)) << 4);
    const int bW2 = 8192 + nB2 * 64 + ((w ^ ((nB2 >> 1) & 3)) << 4);

    // ---- global load columns (clamped in-bounds; garbage rows/cols never consumed) ----
    const int mcol  = min(w1base + l, W1_ - 1);   // tile 2 rows >=56 are garbage, masked at store
    const int ncol0 = l;
    const int ncol1 = 64 + l;
    const int ncol2 = min(128 + l, W2_ - 1);      // B rows 184..191 garbage, never stored
    const int kb0   = b * C_ + 8 * w;             // + kc*32 + j  -> k index

    float aS[8], bS0[8], bS1[8], bS2[8];

    // issue 32 dword loads for chunk kc_ (thread: fixed column, 8 consecutive k = its k-group)
#define LOADCHUNK(kc_) do {                                                        \
        const float* aB = fmap1 + ((kb0 + (kc_) * 32) * H_ + h) * W1_;             \
        const float* bB = fmap2 + ((kb0 + (kc_) * 32) * H_ + h) * W2_;             \
        _Pragma("unroll")                                                          \
        for (int j = 0; j < 8; ++j) {                                              \
            aS[j]  = aB[j * HW1 + mcol];                                           \
            bS0[j] = bB[j * HW2 + ncol0];                                          \
            bS1[j] = bB[j * HW2 + ncol1];                                          \
            bS2[j] = bB[j * HW2 + ncol2];                                          \
        }                                                                          \
    } while (0)

    // convert staged regs to bf16 hi/lo and ds_write_b128 into swizzled LDS
#define CONVWRITE do {                                                             \
        short8 vh, vl;                                                             \
        _Pragma("unroll") for (int j = 0; j < 8; ++j) { HL t = bsplit(aS[j]);  vh[j] = t.hi; vl[j] = t.lo; } \
        *(short8*)(ldsRaw + aW) = vh; *(short8*)(ldsRaw + 4096 + aW) = vl;         \
        _Pragma("unroll") for (int j = 0; j < 8; ++j) { HL t = bsplit(bS0[j]); vh[j] = t.hi; vl[j] = t.lo; } \
        *(short8*)(ldsRaw + bW0) = vh; *(short8*)(ldsRaw + 12288 + bW0) = vl;      \
        _Pragma("unroll") for (int j = 0; j < 8; ++j) { HL t = bsplit(bS1[j]); vh[j] = t.hi; vl[j] = t.lo; } \
        *(short8*)(ldsRaw + bW1) = vh; *(short8*)(ldsRaw + 12288 + bW1) = vl;      \
        _Pragma("unroll") for (int j = 0; j < 8; ++j) { HL t = bsplit(bS2[j]); vh[j] = t.hi; vl[j] = t.lo; } \
        *(short8*)(ldsRaw + bW2) = vh; *(short8*)(ldsRaw + 12288 + bW2) = vl;      \
    } while (0)

    f32x4 acc[12];
    #pragma unroll
    for (int nt = 0; nt < 12; ++nt) acc[nt] = (f32x4)(0.f);

    // 3-pass bf16-split MFMA over one staged chunk: D += Ahi*Bhi + Ahi*Blo + Alo*Bhi
#define COMPUTE do {                                                               \
        const short8 ah = *(const short8*)(ldsRaw + aOff);                         \
        const short8 al = *(const short8*)(ldsRaw + 4096 + aOff);                  \
        _Pragma("unroll")                                                          \
        for (int nt = 0; nt < 12; ++nt) {                                          \
            const short8 bhv = *(const short8*)(ldsRaw + bOff[nt]);                \
            const short8 blv = *(const short8*)(ldsRaw + 12288 + bOff[nt]);        \
            acc[nt] = __builtin_amdgcn_mfma_f32_16x16x32_bf16(ah, bhv, acc[nt], 0, 0, 0); \
            acc[nt] = __builtin_amdgcn_mfma_f32_16x16x32_bf16(ah, blv, acc[nt], 0, 0, 0); \
            acc[nt] = __builtin_amdgcn_mfma_f32_16x16x32_bf16(al, bhv, acc[nt], 0, 0, 0); \
        }                                                                          \
    } while (0)

    // ---- K pipeline: issue-early reg staging (T14), plain __syncthreads, no asm clobbers ----
    LOADCHUNK(0);
    CONVWRITE;                 // compiler inserts vmcnt wait before first use
    __syncthreads();
    #pragma unroll 1
    for (int kc = 0; kc < NK; ++kc) {
        if (kc < NK - 1) LOADCHUNK(kc + 1);   // in flight during compute
        COMPUTE;
        if (kc < NK - 1) {
            __syncthreads();                  // all waves done reading this chunk
            CONVWRITE;
            __syncthreads();                  // writes visible
        }
    }
    __syncthreads();                          // last chunk reads done before LDS reuse

    // ---- fused epilogue: 4 chunks of 16 rows (wave q owns chunk q's corr rows) ----
    float* corrS = ldsF;                      // [16][192]
    float* pyr   = ldsF + 3072;               // [16][161]: lvl1[92] lvl2[46] lvl3[23]
    constexpr float scale = 0.0625f;          // 1/sqrt(256)

    for (int q = 0; q < 4; ++q) {
        if (w == q) {
            // D layout (m89-verified): col = lane&15, row = (lane>>4)*4 + reg
            #pragma unroll
            for (int nt = 0; nt < 12; ++nt)
                #pragma unroll
                for (int r = 0; r < 4; ++r)
                    corrS[(kg * 4 + r) * 192 + nt * 16 + lm] = acc[nt][r] * scale;
        }
        __syncthreads();

        // pooled pyramid levels (direct from level0)
        for (int e = tid; e < 16 * 161; e += 256) {
            const int rI = e / 161;
            const int p  = e - rI * 161;
            const float* row = corrS + rI * 192;
            float v;
            if (p < 92) {
                const int j = 2 * p;
                v = 0.5f * (row[j] + row[j + 1]);
            } else if (p < 138) {
                const int j = (p - 92) * 4;
                v = 0.25f * (row[j] + row[j + 1] + row[j + 2] + row[j + 3]);
            } else {
                const int j = (p - 138) * 8;
                v = 0.125f * (row[j] + row[j+1] + row[j+2] + row[j+3]
                             + row[j+4] + row[j+5] + row[j+6] + row[j+7]);
            }
            pyr[rI * 161 + p] = v;
        }
        __syncthreads();

        // Gaussian sampling: 72 channels x 16 rows; 16 consecutive lanes share a channel
        for (int t = tid; t < CH * 16; t += 256) {
            const int ch = t >> 4;
            const int r  = t & 15;
            const int w1 = w1base + q * 16 + r;
            if (w1 < W1_) {
                const int lvl = ch / (G_ * S_);
                const int rem = ch - lvl * (G_ * S_);
                const int g   = rem / S_;
                const int s   = rem - g * S_;
                const int cix = ((b * G_ + g) * H_ + h) * W1_ + w1;
                const float x  = (float)(s - S_ / 2) * sigma[cix] + coords[cix];
                const float xi = x * (1.0f / (float)(1 << lvl));
                const int   Wl = W2_ >> lvl;
                const float x0 = floorf(xi);
                const float wr = xi - x0;
                const int i0 = (int)x0;
                const int i1 = i0 + 1;
                const float* rowp = (lvl == 0) ? (corrS + r * 192)
                                  : (pyr + r * 161 + ((lvl == 1) ? 0 : (lvl == 2) ? 92 : 138));
                const int i0c = min(max(i0, 0), Wl - 1);
                const int i1c = min(max(i1, 0), Wl - 1);
                const float v0 = (i0 >= 0 && i0 < Wl) ? rowp[i0c] : 0.f;
                const float v1 = (i1 >= 0 && i1 < Wl) ? rowp[i1c] : 0.f;
                out[((b * CH + ch) * H_ + h) * W1_ + w1] = (1.f - wr) * v0 + wr * v1;
            }
        }
        __syncthreads();
    }
#undef LOADCHUNK
#undef CONVWRITE
#undef COMPUTE
}

extern "C" void kernel_launch(void* const* d_in, const int* in_sizes, int n_in,
                              void* d_out, int out_size, void* d_ws, size_t ws_size,
                              hipStream_t stream) {
    const float* fmap1  = (const float*)d_in[0];
    const float* fmap2  = (const float*)d_in[1];
    const float* coords = (const float*)d_in[2];
    const float* sigma  = (const float*)d_in[3];
    float* out = (float*)d_out;

    dim3 grid((W1_ + TM - 1) / TM, B_ * H_);   // 3 x 320
    corr1d_mfma<<<grid, 256, 0, stream>>>(fmap1, fmap2, coords, sigma, out);
}